// Round 5
// baseline (225.634 us; speedup 1.0000x reference)
//
#include <hip/hip_runtime.h>
#include <hip/hip_bf16.h>
#include <cstdint>

typedef float f32x4 __attribute__((ext_vector_type(4)));
typedef short bf16x8 __attribute__((ext_vector_type(8)));
typedef short short8 __attribute__((ext_vector_type(8)));

#define CIN   128
#define WIMG  56
#define HWSZ  3136      // 56*56
#define OCH   256
#define HP    58
#define WP    58

// ---- prep A: border-zero (456 blocks) + weight repack (1152 blocks), merged ----
__global__ void small_prep(const float* __restrict__ wsrc,
                           __hip_bfloat16* __restrict__ wb,
                           __hip_bfloat16* __restrict__ xb) {
    int bidx = blockIdx.x;
    if (bidx < 456) {
        int idx = bidx * 256 + threadIdx.x;   // 116736 = 32*228*16
        int c8  = idx & 15;
        int t   = idx >> 4;
        int b   = t / 228;
        int pos = t - b * 228;
        int h, w;
        if (pos < 58)       { h = 0;             w = pos; }
        else if (pos < 116) { h = 57;            w = pos - 58; }
        else if (pos < 172) { h = pos - 116 + 1; w = 0; }
        else                { h = pos - 172 + 1; w = 57; }
        uint4 z = {0, 0, 0, 0};
        *(uint4*)((char*)xb + (((size_t)(b * HP + h) * WP + w) * CIN + c8 * 8) * 2) = z;
    } else {
        int idx = (bidx - 456) * 256 + threadIdx.x;   // 294912 = 9*256*128
        int c    = idx & 127;
        int rest = idx >> 7;
        int o    = rest & 255;
        int ij   = rest >> 8;
        wb[idx] = __float2bfloat16(wsrc[((size_t)o * CIN + c) * 9 + ij]);
    }
}

// ---- prep B: x [B][C][H][W] f32 -> xb padded NHWC bf16 [B][58][58][128], 16B stores ----
__global__ __launch_bounds__(256)
void cast_transpose_x(const float* __restrict__ x,
                      __hip_bfloat16* __restrict__ xb) {
    __shared__ float tile[64][33];
    const int hw0 = blockIdx.x * 32;
    const int c0  = blockIdx.y * 64;
    const int b   = blockIdx.z;

    const int lx = threadIdx.x & 31;
    const int lc = threadIdx.x >> 5;
    const float* src = x + ((size_t)(b * CIN + c0 + lc) * HWSZ) + hw0 + lx;
#pragma unroll
    for (int k = 0; k < 8; ++k)
        tile[lc + k * 8][lx] = src[(size_t)(k * 8) * HWSZ];
    __syncthreads();

    const int slot = threadIdx.x & 7;
    const int hwl  = threadIdx.x >> 3;
    int hw = hw0 + hwl;
    int h = hw / WIMG;
    int w = hw - h * WIMG;
    short8 v;
#pragma unroll
    for (int j = 0; j < 8; ++j) {
        __hip_bfloat16 hb = __float2bfloat16(tile[slot * 8 + j][hwl]);
        v[j] = *reinterpret_cast<short*>(&hb);
    }
    *(short8*)(xb + (((size_t)b * HP + (h + 1)) * WP + (w + 1)) * CIN + c0 + slot * 8) = v;
}

// ---- async global->LDS 16B ----
__device__ __forceinline__ void gload16(const void* g, void* l) {
    __builtin_amdgcn_global_load_lds(
        (const __attribute__((address_space(1))) unsigned*)g,
        (__attribute__((address_space(3))) unsigned*)l,
        16, 0, 0);
}

// ---- main: 256x256, BK=64, 8 waves (2Mx4N), 8-phase + register read-ahead ----
__global__ __launch_bounds__(512, 2)
void conv_gemm(const __hip_bfloat16* __restrict__ xb,
               const __hip_bfloat16* __restrict__ wb,
               const float* __restrict__ bias,
               float* __restrict__ out) {
    extern __shared__ __attribute__((aligned(16))) char smem[];  // 131072

    const int tid = threadIdx.x;
    const int wv  = tid >> 6;
    const int ln  = tid & 63;

    int bid = blockIdx.x;
    bid = (bid & 7) * 49 + (bid >> 3);        // XCD swizzle: 392 = 8*49, bijective
    const int m0 = bid * 256;

    // ---- staging addresses (pre-swizzled source, linear LDS dest) ----
    const int srow = tid >> 3;
    const int cs   = tid & 7;
    const int colsrc = ((cs * 16) ^ ((srow & 7) << 4)) >> 1;
    int aOff[4], bOff[4];
#pragma unroll
    for (int q = 0; q < 4; ++q) {
        int row = q * 64 + srow;
        int p  = m0 + row;
        int b  = p / HWSZ;
        int hw = p - b * HWSZ;
        int h  = hw / WIMG;
        int w  = hw - h * WIMG;
        aOff[q] = ((b * HP + h) * WP + w) * CIN + colsrc;
        bOff[q] = row * CIN + colsrc;
    }
    const int ldsd = tid * 16;

#define SA(buf,q,offA_) gload16(xb + aOff[q] + (offA_), smem + (buf)*65536 + (q)*8192 + ldsd)
#define SBW(buf,q,offB_) gload16(wb + bOff[q] + (offB_), smem + (buf)*65536 + 32768 + (q)*8192 + ldsd)

    // ---- compute-side constants ----
    const int wm  = wv >> 2;
    const int wn  = wv & 3;
    const int fr  = ln & 15;
    const int kby = (ln >> 4) * 16;
    const int swz = (ln & 7) << 4;

    f32x4 acc[8][4] = {};
    bf16x8 af0[4][2], af1[4][2], bq0E[2][2], bq0O[2][2], bq1[2][2];

#define READ_AF(base, mh, dst) do {                                           \
    _Pragma("unroll") for (int mi = 0; mi < 4; ++mi)                          \
    _Pragma("unroll") for (int kk = 0; kk < 2; ++kk)                          \
        dst[mi][kk] = *(const bf16x8*)((base) +                               \
            (wm*128 + (mh)*64 + mi*16 + fr)*128 + ((kk*64 + kby) ^ swz));     \
} while (0)

#define READ_BF(base, nh, dst) do {                                           \
    _Pragma("unroll") for (int ni = 0; ni < 2; ++ni)                          \
    _Pragma("unroll") for (int kk = 0; kk < 2; ++kk)                          \
        dst[ni][kk] = *(const bf16x8*)((base) + 32768 +                       \
            (wn*64 + (nh)*32 + ni*16 + fr)*128 + ((kk*64 + kby) ^ swz));      \
} while (0)

#define MQ(mh, nh, A, B) do {                                                 \
    _Pragma("unroll") for (int kk = 0; kk < 2; ++kk)                          \
    _Pragma("unroll") for (int mi = 0; mi < 4; ++mi)                          \
    _Pragma("unroll") for (int ni = 0; ni < 2; ++ni)                          \
        acc[(mh)*4+mi][(nh)*2+ni] = __builtin_amdgcn_mfma_f32_16x16x32_bf16(  \
            A[mi][kk], B[ni][kk], acc[(mh)*4+mi][(nh)*2+ni], 0, 0, 0);        \
} while (0)

#define LGKM(N) do { asm volatile("s_waitcnt lgkmcnt(" #N ")" ::: "memory");  \
                     __builtin_amdgcn_sched_barrier(0); } while (0)
#define VMW(N)  do { asm volatile("s_waitcnt vmcnt(" #N ")" ::: "memory");    \
                     __builtin_amdgcn_sched_barrier(0); } while (0)
#define FEN     __builtin_amdgcn_sched_barrier(0)
#define BAR     __builtin_amdgcn_s_barrier()
#define PRIO_MQ(mh, nh, A, B) do { __builtin_amdgcn_s_setprio(1);             \
    MQ(mh, nh, A, B); __builtin_amdgcn_s_setprio(0); FEN; } while (0)

    const char* base0 = smem;
    const char* base1 = smem + 65536;

    // ---- prologue ----
    // tile0 (buf0) all 4 pairs; tile1 (buf1) pairs p0,p1,p2
    SA(0,0,0); SA(0,2,0); SBW(0,0,0); SBW(0,1,0); SBW(0,2,0); SBW(0,3,0); SA(0,1,0); SA(0,3,0);
    SA(1,0,64); SA(1,2,64); SBW(1,0,64); SBW(1,1,64); SBW(1,2,64); SBW(1,3,64);
    VMW(6);                     // tile0 landed; {t1.p0,p1,p2} in flight
    BAR;
    READ_AF(base0, 0, af0); READ_BF(base0, 0, bq0E); READ_BF(base0, 1, bq1);  // rE_main(t0)
    FEN;

#pragma unroll 1
    for (int i = 0; i < 9; ++i) {
        const int iiA = i / 3,       jjA = i - 3 * iiA;          // tap of tiles 2i,2i+1
        const int iiB = (i + 1) / 3, jjB = (i + 1) - 3 * iiB;    // tap of tiles 2i+2,2i+3
        const int offAO1 = (iiA * WP + jjA) * CIN + 64;          // tile 2i+1 A
        const int offAE2 = (iiB * WP + jjB) * CIN;               // tile 2i+2 A
        const int offBE2 = (i + 1) * (OCH * CIN);                // tile 2i+2 B
        const int offAO3 = offAE2 + 64;                          // tile 2i+3 A
        const int offBO3 = offBE2 + 64;                          // tile 2i+3 B
        const bool pf = (i < 8);

        // ---- P0: MFMA E-Q(0,0); stage o3(t_{2i+1}.p3); read af1(buf0) ----
        LGKM(4);
        SA(1,1,offAO1); SA(1,3,offAO1); FEN;
        PRIO_MQ(0, 0, af0, bq0E);
        READ_AF(base0, 1, af1); FEN;
        BAR;

        // ---- P1: MFMA E-Q(0,1); VMW covers {o0,o1,o2} ----
        LGKM(8);
        PRIO_MQ(0, 1, af0, bq1);
        VMW(2);
        BAR;

        // ---- P2: MFMA E-Q(1,1); read rO_main(buf1) ----
        LGKM(0);
        PRIO_MQ(1, 1, af1, bq1);
        READ_AF(base1, 0, af0); READ_BF(base1, 0, bq0O); READ_BF(base1, 1, bq1); FEN;
        BAR;

        // ---- P3: MFMA E-Q(1,0); stage e0,e1,e2 (t_{2i+2}); VMW covers {o3} ----
        if (pf) { SA(0,0,offAE2); SA(0,2,offAE2);
                  SBW(0,0,offBE2); SBW(0,1,offBE2); SBW(0,2,offBE2); SBW(0,3,offBE2); }
        FEN;
        PRIO_MQ(1, 0, af1, bq0E);
        if (pf) VMW(6); else VMW(0);
        BAR;

        // ---- P4: MFMA O-Q(0,0); stage e3; read af1(buf1) ----
        LGKM(4);
        if (pf) { SA(0,1,offAE2); SA(0,3,offAE2); }
        FEN;
        PRIO_MQ(0, 0, af0, bq0O);
        READ_AF(base1, 1, af1); FEN;
        BAR;

        // ---- P5: MFMA O-Q(0,1); VMW covers {e0,e1,e2} ----
        LGKM(8);
        PRIO_MQ(0, 1, af0, bq1);
        if (pf) VMW(2);
        BAR;

        // ---- P6: MFMA O-Q(1,1); read rE_main(buf0, next iter) ----
        LGKM(0);
        PRIO_MQ(1, 1, af1, bq1);
        if (pf) { READ_AF(base0, 0, af0); READ_BF(base0, 0, bq0E); READ_BF(base0, 1, bq1); }
        FEN;
        BAR;

        // ---- P7: MFMA O-Q(1,0); stage o0,o1,o2 (t_{2i+3}); VMW covers {e3} ----
        if (pf) { SA(1,0,offAO3); SA(1,2,offAO3);
                  SBW(1,0,offBO3); SBW(1,1,offBO3); SBW(1,2,offBO3); SBW(1,3,offBO3); }
        FEN;
        PRIO_MQ(1, 0, af1, bq0O);
        if (pf) { VMW(6); BAR; }
    }
#undef SA
#undef SBW
#undef READ_AF
#undef READ_BF
#undef MQ
#undef PRIO_MQ
#undef LGKM
#undef VMW
#undef FEN
#undef BAR

    // ---- epilogue: C/D map col=ln&15 (n), row=(ln>>4)*4+reg (pixel) ----
    const int laneR4 = (ln >> 4) * 4;
    float bn[4];
#pragma unroll
    for (int ni = 0; ni < 4; ++ni)
        bn[ni] = bias[wn * 64 + ni * 16 + fr];

#pragma unroll
    for (int mi = 0; mi < 8; ++mi) {
        int p0 = m0 + wm * 128 + mi * 16 + laneR4;
        int b  = p0 / HWSZ;
        int hw = p0 - b * HWSZ;
#pragma unroll
        for (int ni = 0; ni < 4; ++ni) {
            int n = wn * 64 + ni * 16 + fr;
            float4 v;
            v.x = acc[mi][ni][0] + bn[ni];
            v.y = acc[mi][ni][1] + bn[ni];
            v.z = acc[mi][ni][2] + bn[ni];
            v.w = acc[mi][ni][3] + bn[ni];
            *(float4*)(out + ((size_t)(b * OCH + n) * HWSZ + hw)) = v;
        }
    }
}

extern "C" void kernel_launch(void* const* d_in, const int* in_sizes, int n_in,
                              void* d_out, int out_size, void* d_ws, size_t ws_size,
                              hipStream_t stream) {
    const float* x    = (const float*)d_in[0];
    const float* w    = (const float*)d_in[1];
    const float* bias = (const float*)d_in[2];
    float* out = (float*)d_out;

    char* ws = (char*)d_ws;
    __hip_bfloat16* xbuf = (__hip_bfloat16*)ws;                   // 27,557,888 B
    __hip_bfloat16* wbuf = (__hip_bfloat16*)(ws + 27557888);      //    589,824 B

    hipFuncSetAttribute(reinterpret_cast<const void*>(conv_gemm),
                        hipFuncAttributeMaxDynamicSharedMemorySize, 131072);

    small_prep<<<1608, 256, 0, stream>>>(w, wbuf, xbuf);
    cast_transpose_x<<<dim3(98, 2, 32), dim3(256), 0, stream>>>(x, xbuf);
    conv_gemm<<<392, 512, 131072, stream>>>(xbuf, wbuf, bias, out);
}

// Round 6
// 221.840 us; speedup vs baseline: 1.0171x; 1.0171x over previous
//
#include <hip/hip_runtime.h>
#include <hip/hip_bf16.h>
#include <cstdint>

typedef float f32x4 __attribute__((ext_vector_type(4)));
typedef short bf16x8 __attribute__((ext_vector_type(8)));
typedef short short8 __attribute__((ext_vector_type(8)));

#define CIN   128
#define WIMG  56
#define HWSZ  3136      // 56*56
#define OCH   256
#define HP    58
#define WP    58

// ---- prep A: border-zero (456 blocks) + weight repack (1152 blocks), merged ----
__global__ void small_prep(const float* __restrict__ wsrc,
                           __hip_bfloat16* __restrict__ wb,
                           __hip_bfloat16* __restrict__ xb) {
    int bidx = blockIdx.x;
    if (bidx < 456) {
        int idx = bidx * 256 + threadIdx.x;   // 116736 = 32*228*16
        int c8  = idx & 15;
        int t   = idx >> 4;
        int b   = t / 228;
        int pos = t - b * 228;
        int h, w;
        if (pos < 58)       { h = 0;             w = pos; }
        else if (pos < 116) { h = 57;            w = pos - 58; }
        else if (pos < 172) { h = pos - 116 + 1; w = 0; }
        else                { h = pos - 172 + 1; w = 57; }
        uint4 z = {0, 0, 0, 0};
        *(uint4*)((char*)xb + (((size_t)(b * HP + h) * WP + w) * CIN + c8 * 8) * 2) = z;
    } else {
        int idx = (bidx - 456) * 256 + threadIdx.x;   // 294912 = 9*256*128
        int c    = idx & 127;
        int rest = idx >> 7;
        int o    = rest & 255;
        int ij   = rest >> 8;
        wb[idx] = __float2bfloat16(wsrc[((size_t)o * CIN + c) * 9 + ij]);
    }
}

// ---- prep B: x [B][C][H][W] f32 -> xb padded NHWC bf16 [B][58][58][128], 16B stores ----
__global__ __launch_bounds__(256)
void cast_transpose_x(const float* __restrict__ x,
                      __hip_bfloat16* __restrict__ xb) {
    __shared__ float tile[64][33];
    const int hw0 = blockIdx.x * 32;
    const int c0  = blockIdx.y * 64;
    const int b   = blockIdx.z;

    const int lx = threadIdx.x & 31;
    const int lc = threadIdx.x >> 5;
    const float* src = x + ((size_t)(b * CIN + c0 + lc) * HWSZ) + hw0 + lx;
#pragma unroll
    for (int k = 0; k < 8; ++k)
        tile[lc + k * 8][lx] = src[(size_t)(k * 8) * HWSZ];
    __syncthreads();

    const int slot = threadIdx.x & 7;
    const int hwl  = threadIdx.x >> 3;
    int hw = hw0 + hwl;
    int h = hw / WIMG;
    int w = hw - h * WIMG;
    short8 v;
#pragma unroll
    for (int j = 0; j < 8; ++j) {
        __hip_bfloat16 hb = __float2bfloat16(tile[slot * 8 + j][hwl]);
        v[j] = *reinterpret_cast<short*>(&hb);
    }
    *(short8*)(xb + (((size_t)b * HP + (h + 1)) * WP + (w + 1)) * CIN + c0 + slot * 8) = v;
}

// ---- async global->LDS 16B ----
__device__ __forceinline__ void gload16(const void* g, void* l) {
    __builtin_amdgcn_global_load_lds(
        (const __attribute__((address_space(1))) unsigned*)g,
        (__attribute__((address_space(3))) unsigned*)l,
        16, 0, 0);
}

// ---- main: 256x256, BK=64, 8 waves (2Mx4N), 8-phase + register read-ahead ----
// LDS (128 KiB) already caps occupancy at 1 block/CU, so request the full
// 256-VGPR budget: launch_bounds(512, >1) caused scratch spill (R5: +190 MB HBM).
__global__ __launch_bounds__(512, 1)
void conv_gemm(const __hip_bfloat16* __restrict__ xb,
               const __hip_bfloat16* __restrict__ wb,
               const float* __restrict__ bias,
               float* __restrict__ out) {
    extern __shared__ __attribute__((aligned(16))) char smem[];  // 131072

    const int tid = threadIdx.x;
    const int wv  = tid >> 6;
    const int ln  = tid & 63;

    int bid = blockIdx.x;
    bid = (bid & 7) * 49 + (bid >> 3);        // XCD swizzle: 392 = 8*49, bijective
    const int m0 = bid * 256;

    // ---- staging addresses (pre-swizzled source, linear LDS dest) ----
    const int srow = tid >> 3;
    const int cs   = tid & 7;
    const int colsrc = ((cs * 16) ^ ((srow & 7) << 4)) >> 1;
    int aOff[4], bOff[4];
#pragma unroll
    for (int q = 0; q < 4; ++q) {
        int row = q * 64 + srow;
        int p  = m0 + row;
        int b  = p / HWSZ;
        int hw = p - b * HWSZ;
        int h  = hw / WIMG;
        int w  = hw - h * WIMG;
        aOff[q] = ((b * HP + h) * WP + w) * CIN + colsrc;
        bOff[q] = row * CIN + colsrc;
    }
    const int ldsd = tid * 16;

#define SA(buf,q,offA_) gload16(xb + aOff[q] + (offA_), smem + (buf)*65536 + (q)*8192 + ldsd)
#define SBW(buf,q,offB_) gload16(wb + bOff[q] + (offB_), smem + (buf)*65536 + 32768 + (q)*8192 + ldsd)

    // ---- compute-side constants ----
    const int wm  = wv >> 2;
    const int wn  = wv & 3;
    const int fr  = ln & 15;
    const int kby = (ln >> 4) * 16;
    const int swz = (ln & 7) << 4;

    f32x4 acc[8][4] = {};
    bf16x8 af0[4][2], af1[4][2], bq0E[2][2], bq0O[2][2], bq1[2][2];

#define READ_AF(base, mh, dst) do {                                           \
    _Pragma("unroll") for (int mi = 0; mi < 4; ++mi)                          \
    _Pragma("unroll") for (int kk = 0; kk < 2; ++kk)                          \
        dst[mi][kk] = *(const bf16x8*)((base) +                               \
            (wm*128 + (mh)*64 + mi*16 + fr)*128 + ((kk*64 + kby) ^ swz));     \
} while (0)

#define READ_BF(base, nh, dst) do {                                           \
    _Pragma("unroll") for (int ni = 0; ni < 2; ++ni)                          \
    _Pragma("unroll") for (int kk = 0; kk < 2; ++kk)                          \
        dst[ni][kk] = *(const bf16x8*)((base) + 32768 +                       \
            (wn*64 + (nh)*32 + ni*16 + fr)*128 + ((kk*64 + kby) ^ swz));      \
} while (0)

#define MQ(mh, nh, A, B) do {                                                 \
    _Pragma("unroll") for (int kk = 0; kk < 2; ++kk)                          \
    _Pragma("unroll") for (int mi = 0; mi < 4; ++mi)                          \
    _Pragma("unroll") for (int ni = 0; ni < 2; ++ni)                          \
        acc[(mh)*4+mi][(nh)*2+ni] = __builtin_amdgcn_mfma_f32_16x16x32_bf16(  \
            A[mi][kk], B[ni][kk], acc[(mh)*4+mi][(nh)*2+ni], 0, 0, 0);        \
} while (0)

#define LGKM(N) do { asm volatile("s_waitcnt lgkmcnt(" #N ")" ::: "memory");  \
                     __builtin_amdgcn_sched_barrier(0); } while (0)
#define VMW(N)  do { asm volatile("s_waitcnt vmcnt(" #N ")" ::: "memory");    \
                     __builtin_amdgcn_sched_barrier(0); } while (0)
#define FEN     __builtin_amdgcn_sched_barrier(0)
#define BAR     __builtin_amdgcn_s_barrier()
#define PRIO_MQ(mh, nh, A, B) do { __builtin_amdgcn_s_setprio(1);             \
    MQ(mh, nh, A, B); __builtin_amdgcn_s_setprio(0); FEN; } while (0)

    const char* base0 = smem;
    const char* base1 = smem + 65536;

    // ---- prologue ----
    // tile0 (buf0) all 4 pairs; tile1 (buf1) pairs p0,p1,p2
    SA(0,0,0); SA(0,2,0); SBW(0,0,0); SBW(0,1,0); SBW(0,2,0); SBW(0,3,0); SA(0,1,0); SA(0,3,0);
    SA(1,0,64); SA(1,2,64); SBW(1,0,64); SBW(1,1,64); SBW(1,2,64); SBW(1,3,64);
    VMW(6);                     // tile0 landed; {t1.p0,p1,p2} in flight
    BAR;
    READ_AF(base0, 0, af0); READ_BF(base0, 0, bq0E); READ_BF(base0, 1, bq1);  // rE_main(t0)
    FEN;

#pragma unroll 1
    for (int i = 0; i < 9; ++i) {
        const int iiA = i / 3,       jjA = i - 3 * iiA;          // tap of tiles 2i,2i+1
        const int iiB = (i + 1) / 3, jjB = (i + 1) - 3 * iiB;    // tap of tiles 2i+2,2i+3
        const int offAO1 = (iiA * WP + jjA) * CIN + 64;          // tile 2i+1 A
        const int offAE2 = (iiB * WP + jjB) * CIN;               // tile 2i+2 A
        const int offBE2 = (i + 1) * (OCH * CIN);                // tile 2i+2 B
        const int offAO3 = offAE2 + 64;                          // tile 2i+3 A
        const int offBO3 = offBE2 + 64;                          // tile 2i+3 B
        const bool pf = (i < 8);

        // ---- P0: MFMA E-Q(0,0); stage o3(t_{2i+1}.p3); read af1(buf0) ----
        LGKM(4);
        SA(1,1,offAO1); SA(1,3,offAO1); FEN;
        PRIO_MQ(0, 0, af0, bq0E);
        READ_AF(base0, 1, af1); FEN;
        BAR;

        // ---- P1: MFMA E-Q(0,1); VMW covers {o0,o1,o2} ----
        LGKM(8);
        PRIO_MQ(0, 1, af0, bq1);
        VMW(2);
        BAR;

        // ---- P2: MFMA E-Q(1,1); read rO_main(buf1) ----
        LGKM(0);
        PRIO_MQ(1, 1, af1, bq1);
        READ_AF(base1, 0, af0); READ_BF(base1, 0, bq0O); READ_BF(base1, 1, bq1); FEN;
        BAR;

        // ---- P3: MFMA E-Q(1,0); stage e0,e1,e2 (t_{2i+2}); VMW covers {o3} ----
        if (pf) { SA(0,0,offAE2); SA(0,2,offAE2);
                  SBW(0,0,offBE2); SBW(0,1,offBE2); SBW(0,2,offBE2); SBW(0,3,offBE2); }
        FEN;
        PRIO_MQ(1, 0, af1, bq0E);
        if (pf) VMW(6); else VMW(0);
        BAR;

        // ---- P4: MFMA O-Q(0,0); stage e3; read af1(buf1) ----
        LGKM(4);
        if (pf) { SA(0,1,offAE2); SA(0,3,offAE2); }
        FEN;
        PRIO_MQ(0, 0, af0, bq0O);
        READ_AF(base1, 1, af1); FEN;
        BAR;

        // ---- P5: MFMA O-Q(0,1); VMW covers {e0,e1,e2} ----
        LGKM(8);
        PRIO_MQ(0, 1, af0, bq1);
        if (pf) VMW(2);
        BAR;

        // ---- P6: MFMA O-Q(1,1); read rE_main(buf0, next iter) ----
        LGKM(0);
        PRIO_MQ(1, 1, af1, bq1);
        if (pf) { READ_AF(base0, 0, af0); READ_BF(base0, 0, bq0E); READ_BF(base0, 1, bq1); }
        FEN;
        BAR;

        // ---- P7: MFMA O-Q(1,0); stage o0,o1,o2 (t_{2i+3}); VMW covers {e3} ----
        if (pf) { SA(1,0,offAO3); SA(1,2,offAO3);
                  SBW(1,0,offBO3); SBW(1,1,offBO3); SBW(1,2,offBO3); SBW(1,3,offBO3); }
        FEN;
        PRIO_MQ(1, 0, af1, bq0O);
        if (pf) { VMW(6); BAR; }
    }
#undef SA
#undef SBW
#undef READ_AF
#undef READ_BF
#undef MQ
#undef PRIO_MQ
#undef LGKM
#undef VMW
#undef FEN
#undef BAR

    // ---- epilogue: C/D map col=ln&15 (n), row=(ln>>4)*4+reg (pixel) ----
    const int laneR4 = (ln >> 4) * 4;
    float bn[4];
#pragma unroll
    for (int ni = 0; ni < 4; ++ni)
        bn[ni] = bias[wn * 64 + ni * 16 + fr];

#pragma unroll
    for (int mi = 0; mi < 8; ++mi) {
        int p0 = m0 + wm * 128 + mi * 16 + laneR4;
        int b  = p0 / HWSZ;
        int hw = p0 - b * HWSZ;
#pragma unroll
        for (int ni = 0; ni < 4; ++ni) {
            int n = wn * 64 + ni * 16 + fr;
            float4 v;
            v.x = acc[mi][ni][0] + bn[ni];
            v.y = acc[mi][ni][1] + bn[ni];
            v.z = acc[mi][ni][2] + bn[ni];
            v.w = acc[mi][ni][3] + bn[ni];
            *(float4*)(out + ((size_t)(b * OCH + n) * HWSZ + hw)) = v;
        }
    }
}

extern "C" void kernel_launch(void* const* d_in, const int* in_sizes, int n_in,
                              void* d_out, int out_size, void* d_ws, size_t ws_size,
                              hipStream_t stream) {
    const float* x    = (const float*)d_in[0];
    const float* w    = (const float*)d_in[1];
    const float* bias = (const float*)d_in[2];
    float* out = (float*)d_out;

    char* ws = (char*)d_ws;
    __hip_bfloat16* xbuf = (__hip_bfloat16*)ws;                   // 27,557,888 B
    __hip_bfloat16* wbuf = (__hip_bfloat16*)(ws + 27557888);      //    589,824 B

    hipFuncSetAttribute(reinterpret_cast<const void*>(conv_gemm),
                        hipFuncAttributeMaxDynamicSharedMemorySize, 131072);

    small_prep<<<1608, 256, 0, stream>>>(w, wbuf, xbuf);
    cast_transpose_x<<<dim3(98, 2, 32), dim3(256), 0, stream>>>(x, xbuf);
    conv_gemm<<<392, 512, 131072, stream>>>(xbuf, wbuf, bias, out);
}

// Round 7
// 139.261 us; speedup vs baseline: 1.6202x; 1.5930x over previous
//
#include <hip/hip_runtime.h>
#include <hip/hip_bf16.h>
#include <cstdint>

typedef float f32x4 __attribute__((ext_vector_type(4)));
typedef short bf16x8 __attribute__((ext_vector_type(8)));
typedef short short8 __attribute__((ext_vector_type(8)));

#define CIN   128
#define WIMG  56
#define HWSZ  3136      // 56*56
#define OCH   256
#define HP    58
#define WP    58

// ---- prep A: border-zero (456 blocks) + weight repack (1152 blocks), merged ----
__global__ void small_prep(const float* __restrict__ wsrc,
                           __hip_bfloat16* __restrict__ wb,
                           __hip_bfloat16* __restrict__ xb) {
    int bidx = blockIdx.x;
    if (bidx < 456) {
        int idx = bidx * 256 + threadIdx.x;   // 116736 = 32*228*16
        int c8  = idx & 15;
        int t   = idx >> 4;
        int b   = t / 228;
        int pos = t - b * 228;
        int h, w;
        if (pos < 58)       { h = 0;             w = pos; }
        else if (pos < 116) { h = 57;            w = pos - 58; }
        else if (pos < 172) { h = pos - 116 + 1; w = 0; }
        else                { h = pos - 172 + 1; w = 57; }
        uint4 z = {0, 0, 0, 0};
        *(uint4*)((char*)xb + (((size_t)(b * HP + h) * WP + w) * CIN + c8 * 8) * 2) = z;
    } else {
        int idx = (bidx - 456) * 256 + threadIdx.x;   // 294912 = 9*256*128
        int c    = idx & 127;
        int rest = idx >> 7;
        int o    = rest & 255;
        int ij   = rest >> 8;
        wb[idx] = __float2bfloat16(wsrc[((size_t)o * CIN + c) * 9 + ij]);
    }
}

// ---- prep B: x [B][C][H][W] f32 -> xb padded NHWC bf16 [B][58][58][128], 16B stores ----
__global__ __launch_bounds__(256)
void cast_transpose_x(const float* __restrict__ x,
                      __hip_bfloat16* __restrict__ xb) {
    __shared__ float tile[64][33];
    const int hw0 = blockIdx.x * 32;
    const int c0  = blockIdx.y * 64;
    const int b   = blockIdx.z;

    const int lx = threadIdx.x & 31;
    const int lc = threadIdx.x >> 5;
    const float* src = x + ((size_t)(b * CIN + c0 + lc) * HWSZ) + hw0 + lx;
#pragma unroll
    for (int k = 0; k < 8; ++k)
        tile[lc + k * 8][lx] = src[(size_t)(k * 8) * HWSZ];
    __syncthreads();

    const int slot = threadIdx.x & 7;
    const int hwl  = threadIdx.x >> 3;
    int hw = hw0 + hwl;
    int h = hw / WIMG;
    int w = hw - h * WIMG;
    short8 v;
#pragma unroll
    for (int j = 0; j < 8; ++j) {
        __hip_bfloat16 hb = __float2bfloat16(tile[slot * 8 + j][hwl]);
        v[j] = *reinterpret_cast<short*>(&hb);
    }
    *(short8*)(xb + (((size_t)b * HP + (h + 1)) * WP + (w + 1)) * CIN + c0 + slot * 8) = v;
}

// ---- async global->LDS 16B ----
__device__ __forceinline__ void gload16(const void* g, void* l) {
    __builtin_amdgcn_global_load_lds(
        (const __attribute__((address_space(1))) unsigned*)g,
        (__attribute__((address_space(3))) unsigned*)l,
        16, 0, 0);
}

// ---- main: 256x256 tile, BK=64, 8 waves (2Mx4N), A-only LDS (static 64KB ->
// 2 blocks/CU, all 392 blocks co-resident), B weights global->reg from L2 ----
__global__ __launch_bounds__(512)
void conv_gemm(const __hip_bfloat16* __restrict__ xb,
               const __hip_bfloat16* __restrict__ wb,
               const float* __restrict__ bias,
               float* __restrict__ out) {
    __shared__ __attribute__((aligned(16))) char smem[65536];  // 2 bufs x A[256][64]bf16

    const int tid = threadIdx.x;
    const int wv  = tid >> 6;
    const int ln  = tid & 63;

    int bid = blockIdx.x;
    bid = (bid & 7) * 49 + (bid >> 3);        // XCD swizzle: 392 = 8*49, bijective
    const int m0 = bid * 256;

    // ---- A staging addresses (pre-swizzled source, linear LDS dest) ----
    const int srow = tid >> 3;
    const int cs   = tid & 7;
    const int colsrc = ((cs * 16) ^ ((srow & 7) << 4)) >> 1;
    int aOff[4];
#pragma unroll
    for (int q = 0; q < 4; ++q) {
        int row = q * 64 + srow;
        int p  = m0 + row;
        int b  = p / HWSZ;
        int hw = p - b * HWSZ;
        int h  = hw / WIMG;
        int w  = hw - h * WIMG;
        aOff[q] = ((b * HP + h) * WP + w) * CIN + colsrc;
    }
    const int ldsd = tid * 16;

#define SA(buf,q,offA_) gload16(xb + aOff[q] + (offA_), smem + (buf)*32768 + (q)*8192 + ldsd)

    // ---- compute-side constants ----
    const int wm  = wv >> 2;                  // rows [wm*128, +128)
    const int wn  = wv & 3;                   // cols [wn*64, +64)
    const int fr  = ln & 15;
    const int kby = (ln >> 4) * 16;           // bytes within 64-k row
    const int swz = (ln & 7) << 4;

    // per-lane B fragment base: col (wn*64+fr), k-subchunk (ln>>4)*8 elems
    const __hip_bfloat16* bbase = wb + (wn * 64 + fr) * CIN + ((ln >> 4) << 3);

    f32x4 acc[8][4] = {};
    bf16x8 af[4][2], bqE[4][2], bqO[4][2];

#define LOADB(dst, toff) do {                                                 \
    _Pragma("unroll") for (int ni = 0; ni < 4; ++ni)                          \
    _Pragma("unroll") for (int kk = 0; kk < 2; ++kk)                          \
        dst[ni][kk] = *(const bf16x8*)(bbase + (toff) + ni*(16*CIN) + kk*32); \
} while (0)

#define READ_AH(bufbase, mh) do {                                             \
    _Pragma("unroll") for (int mi = 0; mi < 4; ++mi)                          \
    _Pragma("unroll") for (int kk = 0; kk < 2; ++kk)                          \
        af[mi][kk] = *(const bf16x8*)((bufbase) +                             \
            (wm*128 + (mh)*64 + mi*16 + fr)*128 + ((kk*64 + kby) ^ swz));     \
} while (0)

#define MQH(mh, B) do {                                                       \
    _Pragma("unroll") for (int kk = 0; kk < 2; ++kk)                          \
    _Pragma("unroll") for (int mi = 0; mi < 4; ++mi)                          \
    _Pragma("unroll") for (int ni = 0; ni < 4; ++ni)                          \
        acc[(mh)*4+mi][ni] = __builtin_amdgcn_mfma_f32_16x16x32_bf16(         \
            af[mi][kk], B[ni][kk], acc[(mh)*4+mi][ni], 0, 0, 0);              \
} while (0)

#define LGKM0 do { asm volatile("s_waitcnt lgkmcnt(0)" ::: "memory");         \
                   __builtin_amdgcn_sched_barrier(0); } while (0)
#define VM0   do { asm volatile("s_waitcnt vmcnt(0)" ::: "memory");           \
                   __builtin_amdgcn_sched_barrier(0); } while (0)
#define BAR   __builtin_amdgcn_s_barrier()
#define HALF(bufbase, mh, B) do {                                             \
    READ_AH(bufbase, mh); LGKM0;                                              \
    __builtin_amdgcn_s_setprio(1); MQH(mh, B);                                \
    __builtin_amdgcn_s_setprio(0);                                            \
    __builtin_amdgcn_sched_barrier(0); } while (0)

    const char* buf0 = smem;
    const char* buf1 = smem + 32768;

    // ---- prologue: stage tile0->buf0, B(0)->bqE, tile1->buf1, B(1)->bqO ----
    SA(0,0,0); SA(0,1,0); SA(0,2,0); SA(0,3,0);
    LOADB(bqE, 0);
    SA(1,0,64); SA(1,1,64); SA(1,2,64); SA(1,3,64);
    LOADB(bqO, 64);
    asm volatile("s_waitcnt vmcnt(12)" ::: "memory");   // tile0 A+B landed; tile1 in flight
    __builtin_amdgcn_sched_barrier(0);
    BAR;

#pragma unroll 1
    for (int i = 0; i < 9; ++i) {
        // tiles: tE=2i (buf0,bqE), tO=2i+1 (buf1,bqO); prefetch 2i+2, 2i+3 (tap i+1)
        const int iiB = (i + 1) / 3, jjB = (i + 1) - 3 * iiB;
        const int offA2 = (iiB * WP + jjB) * CIN;        // tile 2i+2: tap i+1, ck 0
        const int offB2 = (i + 1) * (OCH * CIN);
        const int offA3 = offA2 + 64;                    // tile 2i+3: tap i+1, ck 64
        const int offB3 = offB2 + 64;
        const bool pf = (i < 8);

        // ---- tile E: compute from buf0 + bqE ----
        HALF(buf0, 0, bqE);
        HALF(buf0, 1, bqE);
        VM0;                 // drains A(2i+1),B(2i+1) (issued ~1 tile ago)
        BAR;                 // publishes buf1; buf0 free for overwrite
        if (pf) { SA(0,0,offA2); SA(0,1,offA2); SA(0,2,offA2); SA(0,3,offA2);
                  LOADB(bqE, offB2); }

        // ---- tile O: compute from buf1 + bqO ----
        HALF(buf1, 0, bqO);
        HALF(buf1, 1, bqO);
        VM0;                 // drains A(2i+2),B(2i+2)
        BAR;                 // publishes buf0; buf1 free
        if (pf) { SA(1,0,offA3); SA(1,1,offA3); SA(1,2,offA3); SA(1,3,offA3);
                  LOADB(bqO, offB3); }
    }
#undef SA
#undef LOADB
#undef READ_AH
#undef MQH
#undef HALF
#undef LGKM0
#undef VM0
#undef BAR

    // ---- epilogue: C/D map col=ln&15 (n), row=(ln>>4)*4+reg (pixel) ----
    const int laneR4 = (ln >> 4) * 4;
    float bn[4];
#pragma unroll
    for (int ni = 0; ni < 4; ++ni)
        bn[ni] = bias[wn * 64 + ni * 16 + fr];

#pragma unroll
    for (int mi = 0; mi < 8; ++mi) {
        int p0 = m0 + wm * 128 + mi * 16 + laneR4;
        int b  = p0 / HWSZ;
        int hw = p0 - b * HWSZ;
#pragma unroll
        for (int ni = 0; ni < 4; ++ni) {
            int n = wn * 64 + ni * 16 + fr;
            float4 v;
            v.x = acc[mi][ni][0] + bn[ni];
            v.y = acc[mi][ni][1] + bn[ni];
            v.z = acc[mi][ni][2] + bn[ni];
            v.w = acc[mi][ni][3] + bn[ni];
            *(float4*)(out + ((size_t)(b * OCH + n) * HWSZ + hw)) = v;
        }
    }
}

extern "C" void kernel_launch(void* const* d_in, const int* in_sizes, int n_in,
                              void* d_out, int out_size, void* d_ws, size_t ws_size,
                              hipStream_t stream) {
    const float* x    = (const float*)d_in[0];
    const float* w    = (const float*)d_in[1];
    const float* bias = (const float*)d_in[2];
    float* out = (float*)d_out;

    char* ws = (char*)d_ws;
    __hip_bfloat16* xbuf = (__hip_bfloat16*)ws;                   // 27,557,888 B
    __hip_bfloat16* wbuf = (__hip_bfloat16*)(ws + 27557888);      //    589,824 B

    small_prep<<<1608, 256, 0, stream>>>(w, wbuf, xbuf);
    cast_transpose_x<<<dim3(98, 2, 32), dim3(256), 0, stream>>>(x, xbuf);
    conv_gemm<<<392, 512, 0, stream>>>(xbuf, wbuf, bias, out);
}

// Round 8
// 108.655 us; speedup vs baseline: 2.0766x; 1.2817x over previous
//
#include <hip/hip_runtime.h>
#include <hip/hip_bf16.h>
#include <cstdint>

typedef float f32x4 __attribute__((ext_vector_type(4)));
typedef short bf16x8 __attribute__((ext_vector_type(8)));
typedef short short8 __attribute__((ext_vector_type(8)));

#define CIN   128
#define WIMG  56
#define HWSZ  3136      // 56*56
#define OCH   256
#define HP    58
#define WP    58

// ---- prep A: border-zero (456 blocks) + weight repack (1152 blocks), merged ----
__global__ void small_prep(const float* __restrict__ wsrc,
                           __hip_bfloat16* __restrict__ wb,
                           __hip_bfloat16* __restrict__ xb) {
    int bidx = blockIdx.x;
    if (bidx < 456) {
        int idx = bidx * 256 + threadIdx.x;   // 116736 = 32*228*16
        int c8  = idx & 15;
        int t   = idx >> 4;
        int b   = t / 228;
        int pos = t - b * 228;
        int h, w;
        if (pos < 58)       { h = 0;             w = pos; }
        else if (pos < 116) { h = 57;            w = pos - 58; }
        else if (pos < 172) { h = pos - 116 + 1; w = 0; }
        else                { h = pos - 172 + 1; w = 57; }
        uint4 z = {0, 0, 0, 0};
        *(uint4*)((char*)xb + (((size_t)(b * HP + h) * WP + w) * CIN + c8 * 8) * 2) = z;
    } else {
        int idx = (bidx - 456) * 256 + threadIdx.x;   // 294912 = 9*256*128
        int c    = idx & 127;
        int rest = idx >> 7;
        int o    = rest & 255;
        int ij   = rest >> 8;
        wb[idx] = __float2bfloat16(wsrc[((size_t)o * CIN + c) * 9 + ij]);
    }
}

// ---- prep B: x [B][C][H][W] f32 -> xb padded NHWC bf16 [B][58][58][128] ----
__global__ __launch_bounds__(256)
void cast_transpose_x(const float* __restrict__ x,
                      __hip_bfloat16* __restrict__ xb) {
    __shared__ float tile[64][33];
    const int hw0 = blockIdx.x * 32;
    const int c0  = blockIdx.y * 64;
    const int b   = blockIdx.z;

    const int lx = threadIdx.x & 31;
    const int lc = threadIdx.x >> 5;
    const float* src = x + ((size_t)(b * CIN + c0 + lc) * HWSZ) + hw0 + lx;
#pragma unroll
    for (int k = 0; k < 8; ++k)
        tile[lc + k * 8][lx] = src[(size_t)(k * 8) * HWSZ];
    __syncthreads();

    const int slot = threadIdx.x & 7;
    const int hwl  = threadIdx.x >> 3;
    int hw = hw0 + hwl;
    int h = hw / WIMG;
    int w = hw - h * WIMG;
    short8 v;
#pragma unroll
    for (int j = 0; j < 8; ++j) {
        __hip_bfloat16 hb = __float2bfloat16(tile[slot * 8 + j][hwl]);
        v[j] = *reinterpret_cast<short*>(&hb);
    }
    *(short8*)(xb + (((size_t)b * HP + (h + 1)) * WP + (w + 1)) * CIN + c0 + slot * 8) = v;
}

// ---- async global->LDS 16B ----
__device__ __forceinline__ void gload16(const void* g, void* l) {
    __builtin_amdgcn_global_load_lds(
        (const __attribute__((address_space(1))) unsigned*)g,
        (__attribute__((address_space(3))) unsigned*)l,
        16, 0, 0);
}

// ---- main: patch-resident implicit conv ----
// BM=224 (4 out rows), BN=256 (all O). Patch = 6 padded rows x 58 x 128ch bf16
// = 89088 B LDS, staged ONCE; K-loop (9 taps x 2 c-chunks) is BARRIER-FREE:
// A = LDS reads at tap-shifted offsets, B = global->reg double-buffer (L2-hot).
// 8 waves (2M x 4N), per-wave out 112x64. acc 112 AGPR + ~140 VGPR < 256 cap.
__global__ __launch_bounds__(512, 2)
void conv_gemm(const __hip_bfloat16* __restrict__ xb,
               const __hip_bfloat16* __restrict__ wb,
               const float* __restrict__ bias,
               float* __restrict__ out) {
    extern __shared__ __attribute__((aligned(16))) char smem[];   // 89088 B

    const int tid = threadIdx.x;
    const int wv  = tid >> 6;
    const int ln  = tid & 63;

    int bid = blockIdx.x;
    bid = (bid & 7) * 56 + (bid >> 3);        // XCD swizzle: 448 = 8*56, bijective
    const int b   = bid / 14;                 // batch
    const int rg  = bid - b * 14;             // row-group (4 out rows)
    const int m0  = b * HWSZ + rg * 224;
    const int h0  = rg * 4;                   // padded input rows h0..h0+5

    // ---- stage patch: 348 pixels x 16 slots = 5568 x 16B (src pre-XOR-swizzled) ----
#pragma unroll
    for (int r = 0; r < 11; ++r) {
        int li = r * 512 + tid;
        if (li < 5568) {
            int pix  = li >> 4;
            int slot = li & 15;
            int lr = pix / 58;
            int lc2 = pix - lr * 58;
            const char* src = (const char*)xb +
                ((((size_t)(b * HP + h0 + lr)) * WP + lc2) << 8) +
                ((slot ^ (pix & 7)) << 4);
            gload16(src, smem + (li << 4));
        }
    }

    // ---- compute-side constants ----
    const int wm  = wv >> 2;                  // 0..1 : rows [wm*112, +112)
    const int wn  = wv & 3;                   // 0..3 : cols [wn*64, +64)
    const int fr  = ln & 15;
    const int kby = (ln >> 4) * 16;           // 16B slot within 128B k-half

    // per-mi pixel index within patch (row-major 58-wide)
    int lpixI[7];
#pragma unroll
    for (int mi = 0; mi < 7; ++mi) {
        int lp = wm * 112 + mi * 16 + fr;     // 0..223
        int lh = lp / 56;
        int lw = lp - lh * 56;
        lpixI[mi] = lh * 58 + lw;
    }

    // per-lane B fragment base (R7-verified mapping)
    const __hip_bfloat16* bbase = wb + (wn * 64 + fr) * CIN + ((ln >> 4) << 3);

    f32x4 acc[7][4] = {};
    bf16x8 bqA[4][2], bqB[4][2];

#define LOADB(dst, toff) do {                                                 \
    _Pragma("unroll") for (int ni = 0; ni < 4; ++ni)                          \
    _Pragma("unroll") for (int kk = 0; kk < 2; ++kk)                          \
        dst[ni][kk] = *(const bf16x8*)(bbase + (toff) + ni*(16*CIN) + kk*32); \
} while (0)

// one 64-k chunk: A from patch LDS (tap-shifted, XOR-swizzled), 56 MFMA
#define TAP(tapoff, ckb, bq) do {                                             \
    _Pragma("unroll") for (int kk = 0; kk < 2; ++kk)                          \
    _Pragma("unroll") for (int mi = 0; mi < 7; ++mi) {                        \
        int px = lpixI[mi] + (tapoff);                                        \
        bf16x8 afr = *(const bf16x8*)(smem + (px << 8) +                      \
                     (((ckb) + kk*64 + kby) ^ ((px & 7) << 4)));              \
        _Pragma("unroll") for (int ni = 0; ni < 4; ++ni)                      \
            acc[mi][ni] = __builtin_amdgcn_mfma_f32_16x16x32_bf16(            \
                afr, bq[ni][kk], acc[mi][ni], 0, 0, 0);                       \
    }                                                                         \
} while (0)

    __syncthreads();                          // patch staged (drains vmcnt)

    LOADB(bqA, 0);                            // tap 0, c-chunk 0
#pragma unroll 1
    for (int i = 0; i < 9; ++i) {
        const int ii = i / 3, jj = i - 3 * ii;
        const int tapoff = ii * 58 + jj;      // pixel offset in patch
        const int offB   = i * (OCH * CIN);

        LOADB(bqB, offB + 64);                // this tap, c-chunk 1
        TAP(tapoff, 0, bqA);                  // chunk 2i
        if (i < 8) LOADB(bqA, offB + OCH * CIN);  // next tap, c-chunk 0
        TAP(tapoff, 128, bqB);                // chunk 2i+1
    }
#undef LOADB
#undef TAP

    // ---- epilogue: C/D map col=ln&15 (n), row=(ln>>4)*4+reg (pixel) ----
    const int laneR4 = (ln >> 4) * 4;
    float bn[4];
#pragma unroll
    for (int ni = 0; ni < 4; ++ni)
        bn[ni] = bias[wn * 64 + ni * 16 + fr];

#pragma unroll
    for (int mi = 0; mi < 7; ++mi) {
        int p0 = m0 + wm * 112 + mi * 16 + laneR4;   // multiple of 4
        int hw = p0 - b * HWSZ;                      // within batch by construction
#pragma unroll
        for (int ni = 0; ni < 4; ++ni) {
            int n = wn * 64 + ni * 16 + fr;
            float4 v;
            v.x = acc[mi][ni][0] + bn[ni];
            v.y = acc[mi][ni][1] + bn[ni];
            v.z = acc[mi][ni][2] + bn[ni];
            v.w = acc[mi][ni][3] + bn[ni];
            *(float4*)(out + ((size_t)(b * OCH + n) * HWSZ + hw)) = v;
        }
    }
}

extern "C" void kernel_launch(void* const* d_in, const int* in_sizes, int n_in,
                              void* d_out, int out_size, void* d_ws, size_t ws_size,
                              hipStream_t stream) {
    const float* x    = (const float*)d_in[0];
    const float* w    = (const float*)d_in[1];
    const float* bias = (const float*)d_in[2];
    float* out = (float*)d_out;

    char* ws = (char*)d_ws;
    __hip_bfloat16* xbuf = (__hip_bfloat16*)ws;                   // 27,557,888 B
    __hip_bfloat16* wbuf = (__hip_bfloat16*)(ws + 27557888);      //    589,824 B

    hipFuncSetAttribute(reinterpret_cast<const void*>(conv_gemm),
                        hipFuncAttributeMaxDynamicSharedMemorySize, 89088);

    small_prep<<<1608, 256, 0, stream>>>(w, wbuf, xbuf);
    cast_transpose_x<<<dim3(98, 2, 32), dim3(256), 0, stream>>>(x, xbuf);
    conv_gemm<<<448, 512, 89088, stream>>>(xbuf, wbuf, bias, out);
}